// Round 1
// baseline (2079.391 us; speedup 1.0000x reference)
//
#include <hip/hip_runtime.h>
#include <math.h>

#define B_  2
#define T_  1024
#define D_  2048
#define H_  16
#define DH_ 128
#define M_  2048          // B_*T_
#define DR_ 1024          // D_/2

// ---------------------------------------------------------------------------
// GEMM: C = act(A * B^T + bias). A:[M,K] rm, B:[N,K] rm.
// OUT_MODE 0: C row-major [M,N].  OUT_MODE 1: heads layout [b,h,t,dh].
// 128x128 tile, BK=8, 256 threads, 8x8 per thread.
// ---------------------------------------------------------------------------
template<int OUT_MODE, bool SILU>
__global__ __launch_bounds__(256)
void gemm_abt(const float* __restrict__ A, const float* __restrict__ Bm,
              const float* __restrict__ bias, float* __restrict__ C,
              int M, int N, int K)
{
  __shared__ float As[8][128];
  __shared__ float Bs[8][128];
  const int tid = threadIdx.x;
  const int m0 = blockIdx.y * 128;
  const int n0 = blockIdx.x * 128;
  const int lr = tid >> 1;          // 0..127 tile row
  const int lk = (tid & 1) << 2;    // 0 or 4
  const int ty = tid >> 4;          // 0..15
  const int tx = tid & 15;          // 0..15

  float acc[8][8];
  #pragma unroll
  for (int i = 0; i < 8; ++i)
    #pragma unroll
    for (int j = 0; j < 8; ++j) acc[i][j] = 0.f;

  const float* ap = A  + (size_t)(m0 + lr) * K + lk;
  const float* bp = Bm + (size_t)(n0 + lr) * K + lk;

  for (int k0 = 0; k0 < K; k0 += 8) {
    float4 av = *(const float4*)(ap + k0);
    float4 bv = *(const float4*)(bp + k0);
    __syncthreads();
    As[lk+0][lr] = av.x; As[lk+1][lr] = av.y; As[lk+2][lr] = av.z; As[lk+3][lr] = av.w;
    Bs[lk+0][lr] = bv.x; Bs[lk+1][lr] = bv.y; Bs[lk+2][lr] = bv.z; Bs[lk+3][lr] = bv.w;
    __syncthreads();
    #pragma unroll
    for (int k = 0; k < 8; ++k) {
      float a[8], b[8];
      *(float4*)(a)     = *(const float4*)&As[k][ty*8];
      *(float4*)(a + 4) = *(const float4*)&As[k][ty*8 + 4];
      *(float4*)(b)     = *(const float4*)&Bs[k][tx*8];
      *(float4*)(b + 4) = *(const float4*)&Bs[k][tx*8 + 4];
      #pragma unroll
      for (int i = 0; i < 8; ++i)
        #pragma unroll
        for (int j = 0; j < 8; ++j)
          acc[i][j] = fmaf(a[i], b[j], acc[i][j]);
    }
  }

  #pragma unroll
  for (int i = 0; i < 8; ++i) {
    const int m = m0 + ty*8 + i;
    #pragma unroll
    for (int jj = 0; jj < 2; ++jj) {
      const int n = n0 + tx*8 + jj*4;
      float vr[4];
      #pragma unroll
      for (int j = 0; j < 4; ++j) {
        float v = acc[i][jj*4 + j];
        if (bias) v += bias[n + j];
        if (SILU) v = v / (1.f + __expf(-v));   // x * sigmoid(x)
        vr[j] = v;
      }
      float4 v4 = make_float4(vr[0], vr[1], vr[2], vr[3]);
      if (OUT_MODE == 0) {
        *(float4*)(C + (size_t)m * N + n) = v4;
      } else {
        const int bb = m >> 10, tt = m & 1023;   // m = b*T + t
        const int hh = n >> 7,  dd = n & 127;    // n = h*DH + dd
        *(float4*)(C + (((size_t)(bb*H_ + hh))*T_ + tt)*DH_ + dd) = v4;
      }
    }
  }
}

// ---------------------------------------------------------------------------
// Causal EMA: s_t = 0.9 s_{t-1} + 0.1 x_t. Windowed scan: 256-step lookback
// (0.9^256 ~ 2e-12, far below tolerance) -> parallel over t-chunks.
// ---------------------------------------------------------------------------
__global__ __launch_bounds__(256)
void ema_kernel(const float* __restrict__ x, float* __restrict__ l2)
{
  const int b  = blockIdx.z;
  const int t0 = blockIdx.y * 128;
  const int d  = blockIdx.x * 256 + threadIdx.x;
  const float* xp = x  + (size_t)b * T_ * D_ + d;
  float*       lp = l2 + (size_t)b * T_ * D_ + d;
  float s = 0.f;
  int ts = t0 - 256; if (ts < 0) ts = 0;
  for (int t = ts; t < t0; ++t)
    s = 0.9f * s + 0.1f * xp[(size_t)t * D_];
  for (int t = t0; t < t0 + 128; ++t) {
    s = 0.9f * s + 0.1f * xp[(size_t)t * D_];
    lp[(size_t)t * D_] = s;
  }
}

// ---------------------------------------------------------------------------
// Router head: lam = softmax(hdn @ rw2^T + rb2). One wave per row.
// ---------------------------------------------------------------------------
__global__ __launch_bounds__(256)
void router_kernel(const float* __restrict__ hdn, const float* __restrict__ rw2,
                   const float* __restrict__ rb2, float* __restrict__ lam)
{
  const int lane = threadIdx.x & 63;
  const int w    = threadIdx.x >> 6;
  const int m    = blockIdx.x * 4 + w;
  const float* hp = hdn + (size_t)m * DR_;
  float s0 = 0.f, s1 = 0.f, s2 = 0.f;
  for (int k = lane * 4; k < DR_; k += 256) {
    float4 h4 = *(const float4*)(hp + k);
    float4 w0 = *(const float4*)(rw2 + k);
    float4 w1 = *(const float4*)(rw2 + DR_ + k);
    float4 w2 = *(const float4*)(rw2 + 2*DR_ + k);
    s0 += h4.x*w0.x + h4.y*w0.y + h4.z*w0.z + h4.w*w0.w;
    s1 += h4.x*w1.x + h4.y*w1.y + h4.z*w1.z + h4.w*w1.w;
    s2 += h4.x*w2.x + h4.y*w2.y + h4.z*w2.z + h4.w*w2.w;
  }
  #pragma unroll
  for (int off = 32; off > 0; off >>= 1) {
    s0 += __shfl_down(s0, off);
    s1 += __shfl_down(s1, off);
    s2 += __shfl_down(s2, off);
  }
  if (lane == 0) {
    s0 += rb2[0]; s1 += rb2[1]; s2 += rb2[2];
    float mx = fmaxf(s0, fmaxf(s1, s2));
    float e0 = __expf(s0 - mx), e1 = __expf(s1 - mx), e2 = __expf(s2 - mx);
    float inv = 1.f / (e0 + e1 + e2);
    lam[(size_t)m*3 + 0] = e0 * inv;
    lam[(size_t)m*3 + 1] = e1 * inv;
    lam[(size_t)m*3 + 2] = e2 * inv;
  }
}

// ---------------------------------------------------------------------------
// fused = lam0*x + lam1*l2 + lam2*l3mem  (in place into the l2 buffer)
// ---------------------------------------------------------------------------
__global__ __launch_bounds__(256)
void fuse_kernel(const float* __restrict__ x, float* __restrict__ l2f,
                 const float* __restrict__ l3m, const float* __restrict__ lam)
{
  const int i4 = blockIdx.x * 256 + threadIdx.x;   // over M_*D_/4
  const int m  = i4 >> 9;                          // D_/4 = 512
  const int c  = (i4 & 511) << 2;
  const int b  = m >> 10;
  const float w0 = lam[m*3+0], w1 = lam[m*3+1], w2 = lam[m*3+2];
  const float4 xv = *(const float4*)(x   + (size_t)m*D_ + c);
  const float4 ev = *(const float4*)(l2f + (size_t)m*D_ + c);
  const float4 gv = *(const float4*)(l3m + (size_t)b*D_ + c);
  float4 r;
  r.x = w0*xv.x + w1*ev.x + w2*gv.x;
  r.y = w0*xv.y + w1*ev.y + w2*gv.y;
  r.z = w0*xv.z + w1*ev.z + w2*gv.z;
  r.w = w0*xv.w + w1*ev.w + w2*gv.w;
  *(float4*)(l2f + (size_t)m*D_ + c) = r;
}

// ---------------------------------------------------------------------------
// Flash-style causal attention, fp32. Br=Bc=32, dh=128. 256 threads.
// q from ws ([b,t,d], head slice), k/v from d_out ([b,h,t,dh]).
// ---------------------------------------------------------------------------
__global__ __launch_bounds__(256)
void flash_attn(const float* __restrict__ qg, const float* __restrict__ kg,
                const float* __restrict__ vg, float* __restrict__ og)
{
  __shared__ float Qs[32][132];
  __shared__ float Ks[32][132];
  __shared__ float Vs[32][132];
  __shared__ float Ss[32][36];
  __shared__ float mrow[32], lrow[32], arow[32];
  const int tid = threadIdx.x;
  const int qt  = blockIdx.x;
  const int bh  = blockIdx.y;
  const int b   = bh >> 4, h = bh & 15;
  const int q0  = qt * 32;

  const float* qsrc = qg + ((size_t)b * T_) * D_ + (size_t)h * DH_;
  for (int i = tid; i < 32*32; i += 256) {
    int r = i >> 5, c4 = (i & 31) << 2;
    *(float4*)&Qs[r][c4] = *(const float4*)(qsrc + (size_t)(q0 + r) * D_ + c4);
  }
  if (tid < 32) { mrow[tid] = -INFINITY; lrow[tid] = 0.f; }

  float oacc[16];
  #pragma unroll
  for (int i = 0; i < 16; ++i) oacc[i] = 0.f;

  const float* kb = kg + (size_t)bh * T_ * DH_;
  const float* vb = vg + (size_t)bh * T_ * DH_;
  const int ty = tid >> 4, tx = tid & 15;            // S: rows 2ty+i, cols 2tx+j
  const int orow = tid >> 3, ocg = (tid & 7) << 2;   // O: row, 4 col-groups
  const float scale = 0.08838834764831845f;          // 1/sqrt(128)

  for (int kt = 0; kt <= qt; ++kt) {
    const int k0 = kt * 32;
    __syncthreads();   // protect Ss/Vs consumers of previous iteration
    for (int i = tid; i < 32*32; i += 256) {
      int r = i >> 5, c4 = (i & 31) << 2;
      *(float4*)&Ks[r][c4] = *(const float4*)(kb + (size_t)(k0 + r) * DH_ + c4);
      *(float4*)&Vs[r][c4] = *(const float4*)(vb + (size_t)(k0 + r) * DH_ + c4);
    }
    __syncthreads();

    float s00 = 0.f, s01 = 0.f, s10 = 0.f, s11 = 0.f;
    #pragma unroll
    for (int k = 0; k < DH_; k += 4) {
      float4 a0 = *(const float4*)&Qs[2*ty][k];
      float4 a1 = *(const float4*)&Qs[2*ty+1][k];
      float4 b0 = *(const float4*)&Ks[2*tx][k];
      float4 b1 = *(const float4*)&Ks[2*tx+1][k];
      s00 += a0.x*b0.x + a0.y*b0.y + a0.z*b0.z + a0.w*b0.w;
      s01 += a0.x*b1.x + a0.y*b1.y + a0.z*b1.z + a0.w*b1.w;
      s10 += a1.x*b0.x + a1.y*b0.y + a1.z*b0.z + a1.w*b0.w;
      s11 += a1.x*b1.x + a1.y*b1.y + a1.z*b1.z + a1.w*b1.w;
    }
    {
      const int gq0 = q0 + 2*ty, gq1 = gq0 + 1;
      const int gk0 = k0 + 2*tx, gk1 = gk0 + 1;
      Ss[2*ty][2*tx]     = (gk0 <= gq0) ? s00*scale : -INFINITY;
      Ss[2*ty][2*tx+1]   = (gk1 <= gq0) ? s01*scale : -INFINITY;
      Ss[2*ty+1][2*tx]   = (gk0 <= gq1) ? s10*scale : -INFINITY;
      Ss[2*ty+1][2*tx+1] = (gk1 <= gq1) ? s11*scale : -INFINITY;
    }
    __syncthreads();
    if (tid < 32) {
      float mo = mrow[tid], mx = mo;
      #pragma unroll
      for (int c = 0; c < 32; ++c) mx = fmaxf(mx, Ss[tid][c]);
      float alpha = __expf(mo - mx);     // exp(-inf)=0 on first tile
      float ls = 0.f;
      #pragma unroll
      for (int c = 0; c < 32; ++c) {
        float p = __expf(Ss[tid][c] - mx);
        Ss[tid][c] = p;
        ls += p;
      }
      mrow[tid] = mx;
      lrow[tid] = lrow[tid]*alpha + ls;
      arow[tid] = alpha;
    }
    __syncthreads();
    const float al = arow[orow];
    #pragma unroll
    for (int i = 0; i < 16; ++i) oacc[i] *= al;
    #pragma unroll 4
    for (int cc = 0; cc < 32; ++cc) {
      const float p = Ss[orow][cc];
      #pragma unroll
      for (int j = 0; j < 4; ++j) {
        float4 vv = *(const float4*)&Vs[cc][j*32 + ocg];
        oacc[j*4+0] += p*vv.x;
        oacc[j*4+1] += p*vv.y;
        oacc[j*4+2] += p*vv.z;
        oacc[j*4+3] += p*vv.w;
      }
    }
  }

  const float inv = 1.f / lrow[orow];
  float* od = og + ((size_t)b*T_ + q0 + orow) * D_ + (size_t)h * DH_;
  #pragma unroll
  for (int j = 0; j < 4; ++j) {
    float4 w4 = make_float4(oacc[j*4]*inv, oacc[j*4+1]*inv,
                            oacc[j*4+2]*inv, oacc[j*4+3]*inv);
    *(float4*)(od + j*32 + ocg) = w4;
  }
}

// ---------------------------------------------------------------------------
extern "C" void kernel_launch(void* const* d_in, const int* in_sizes, int n_in,
                              void* d_out, int out_size, void* d_ws, size_t ws_size,
                              hipStream_t stream)
{
  const float* x   = (const float*)d_in[0];
  const float* l3m = (const float*)d_in[1];
  const float* wq  = (const float*)d_in[2];
  const float* wk  = (const float*)d_in[3];
  const float* wv  = (const float*)d_in[4];
  const float* wo  = (const float*)d_in[5];
  const float* rw1 = (const float*)d_in[6];
  const float* rb1 = (const float*)d_in[7];
  const float* rw2 = (const float*)d_in[8];
  const float* rb2 = (const float*)d_in[9];

  float* out = (float*)d_out;                 // [b,t,d]        4,194,304
  float* kh  = out + 4194304;                 // [b,h,t,dh]     4,194,304
  float* vh  = out + 8388608;                 // [b,h,t,dh]     4,194,304
  float* lam = out + 12582912;                // [b,t,3]            6,144

  float* ws      = (float*)d_ws;
  float* q_ws    = ws;                        // 4,194,304 floats
  float* l2_ws   = ws + 4194304;              // 4,194,304 (becomes `fused` in place)
  float* hdn_ws  = ws + 8388608;              // 2,097,152
  float* attn_ws = ws + 10485760;             // 4,194,304  (total 56 MB)

  dim3 blk(256);

  // 1. q = x @ wq^T
  gemm_abt<0,false><<<dim3(16,16), blk, 0, stream>>>(x, wq, nullptr, q_ws, M_, D_, D_);
  // 2. l2 = causal EMA(x)
  ema_kernel<<<dim3(8,8,2), blk, 0, stream>>>(x, l2_ws);
  // 3. hdn = silu(q @ rw1^T + rb1)
  gemm_abt<0,true><<<dim3(8,16), blk, 0, stream>>>(q_ws, rw1, rb1, hdn_ws, M_, DR_, D_);
  // 4. lam = softmax(hdn @ rw2^T + rb2)  -> d_out lam region
  router_kernel<<<dim3(512), blk, 0, stream>>>(hdn_ws, rw2, rb2, lam);
  // 5. fused = lam0*x + lam1*l2 + lam2*l3  (in place in l2_ws)
  fuse_kernel<<<dim3(4096), blk, 0, stream>>>(x, l2_ws, l3m, lam);
  // 6/7. kh, vh  (direct heads-layout store into d_out)
  gemm_abt<1,false><<<dim3(16,16), blk, 0, stream>>>(l2_ws, wk, nullptr, kh, M_, D_, D_);
  gemm_abt<1,false><<<dim3(16,16), blk, 0, stream>>>(l2_ws, wv, nullptr, vh, M_, D_, D_);
  // 8. causal flash attention -> attn_ws ([b,t,d] merged heads)
  flash_attn<<<dim3(32,32), blk, 0, stream>>>(q_ws, kh, vh, attn_ws);
  // 9. out = attn @ wo^T
  gemm_abt<0,false><<<dim3(16,16), blk, 0, stream>>>(attn_ws, wo, nullptr, out, M_, D_, D_);
}

// Round 3
// 966.040 us; speedup vs baseline: 2.1525x; 2.1525x over previous
//
#include <hip/hip_runtime.h>
#include <hip/hip_bf16.h>
#include <math.h>

#define B_  2
#define T_  1024
#define D_  2048
#define H_  16
#define DH_ 128
#define M_  2048          // B_*T_
#define DR_ 1024          // D_/2

typedef __attribute__((ext_vector_type(8))) short short8;
typedef __attribute__((ext_vector_type(4))) float f32x4;

// async global->LDS, 16B per lane, dest = wave-uniform base + lane*16
__device__ __forceinline__ void gld16(const __hip_bfloat16* g, __hip_bfloat16* l) {
  __builtin_amdgcn_global_load_lds(
      (const __attribute__((address_space(1))) unsigned int*)g,
      (__attribute__((address_space(3))) unsigned int*)l, 16, 0, 0);
}

// ---------------------------------------------------------------------------
// bf16 MFMA GEMM: C = act(A * B^T + bias). A:[M,K] bf16 rm, B:[N,K] bf16 rm.
// 128x128 tile, BK=32, 256 threads (4 waves in 2x2), 4x4 16x16x32 MFMA/wave.
// OUT_MODE 0: C row-major [M,N] fp32 (+ optional bf16 copy Cb).
// OUT_MODE 1: C heads layout [b,h,t,dh] fp32.
// ---------------------------------------------------------------------------
template<int OUT_MODE, bool SILU, bool DUALBF>
__global__ __launch_bounds__(256)
void gemm_mfma(const __hip_bfloat16* __restrict__ A,
               const __hip_bfloat16* __restrict__ Bm,
               const float* __restrict__ bias,
               float* __restrict__ C, __hip_bfloat16* __restrict__ Cb,
               int M, int N, int K)
{
  __shared__ __hip_bfloat16 As[128 * 32];
  __shared__ __hip_bfloat16 Bs[128 * 32];
  const int tid  = threadIdx.x;
  const int wave = tid >> 6;
  const int lane = tid & 63;
  const int m0 = blockIdx.y * 128;
  const int n0 = blockIdx.x * 128;
  const int wm = (wave >> 1) * 64;   // wave's 64-row half
  const int wn = (wave & 1) * 64;    // wave's 64-col half

  // staging: inst (wave*2+j) covers tile rows (wave*2+j)*16 .. +15
  const int srow = lane >> 2;          // 0..15 row within 16-row group
  const int scol = (lane & 3) * 8;     // bf16 element offset in k (16B chunks)
  const __hip_bfloat16* Ag = A  + (size_t)(m0 + wave * 32 + srow) * K + scol;
  const __hip_bfloat16* Bg = Bm + (size_t)(n0 + wave * 32 + srow) * K + scol;
  __hip_bfloat16* Al0 = As + (wave * 2 + 0) * 512;
  __hip_bfloat16* Al1 = As + (wave * 2 + 1) * 512;
  __hip_bfloat16* Bl0 = Bs + (wave * 2 + 0) * 512;
  __hip_bfloat16* Bl1 = Bs + (wave * 2 + 1) * 512;

  const int fr = lane & 15;            // fragment row (m/n index)
  const int fk = (lane >> 4) * 8;      // fragment k offset

  f32x4 acc[4][4];
  #pragma unroll
  for (int i = 0; i < 4; ++i)
    #pragma unroll
    for (int j = 0; j < 4; ++j) acc[i][j] = (f32x4)0.f;

  for (int k0 = 0; k0 < K; k0 += 32) {
    __syncthreads();   // prev iteration's LDS reads done before overwrite
    gld16(Ag + k0,                  Al0);
    gld16(Ag + (size_t)16 * K + k0, Al1);
    gld16(Bg + k0,                  Bl0);
    gld16(Bg + (size_t)16 * K + k0, Bl1);
    __syncthreads();   // staging complete (vmcnt drained by barrier)

    short8 af[4], bfr[4];
    #pragma unroll
    for (int i = 0; i < 4; ++i) {
      af[i]  = *(const short8*)(As + (wm + i * 16 + fr) * 32 + fk);
      bfr[i] = *(const short8*)(Bs + (wn + i * 16 + fr) * 32 + fk);
    }
    #pragma unroll
    for (int i = 0; i < 4; ++i)
      #pragma unroll
      for (int j = 0; j < 4; ++j)
        acc[i][j] = __builtin_amdgcn_mfma_f32_16x16x32_bf16(af[i], bfr[j], acc[i][j], 0, 0, 0);
  }

  // C/D layout (m89-verified): col = lane&15, row = (lane>>4)*4 + reg
  #pragma unroll
  for (int i = 0; i < 4; ++i) {
    #pragma unroll
    for (int j = 0; j < 4; ++j) {
      #pragma unroll
      for (int r = 0; r < 4; ++r) {
        const int row = m0 + wm + i * 16 + (lane >> 4) * 4 + r;
        const int col = n0 + wn + j * 16 + (lane & 15);
        float v = acc[i][j][r];
        if (bias) v += bias[col];
        if (SILU) v = v / (1.f + __expf(-v));
        if (OUT_MODE == 0) {
          const size_t idx = (size_t)row * N + col;
          C[idx] = v;
          if (DUALBF) Cb[idx] = __float2bfloat16(v);
        } else {
          const int bb = row >> 10, tt = row & 1023;   // row = b*T + t
          const int hh = col >> 7,  dd = col & 127;    // col = h*DH + dd
          C[(((size_t)(bb * H_ + hh)) * T_ + tt) * DH_ + dd] = v;
        }
      }
    }
  }
}

// ---------------------------------------------------------------------------
// fp32 -> bf16 conversions for x, wq, wk, wv, wo, rw1 in one launch.
// ---------------------------------------------------------------------------
__global__ __launch_bounds__(256)
void cvt6(const float* __restrict__ s0, const float* __restrict__ s1,
          const float* __restrict__ s2, const float* __restrict__ s3,
          const float* __restrict__ s4, const float* __restrict__ s5,
          __hip_bfloat16* d0, __hip_bfloat16* d1, __hip_bfloat16* d2,
          __hip_bfloat16* d3, __hip_bfloat16* d4, __hip_bfloat16* d5,
          int n0, int n1, int n2, int n3, int n4, int n5)
{
  const float* s; __hip_bfloat16* d; int n;
  switch (blockIdx.y) {
    case 0: s = s0; d = d0; n = n0; break;
    case 1: s = s1; d = d1; n = n1; break;
    case 2: s = s2; d = d2; n = n2; break;
    case 3: s = s3; d = d3; n = n3; break;
    case 4: s = s4; d = d4; n = n4; break;
    default: s = s5; d = d5; n = n5; break;
  }
  const int i = (blockIdx.x * 256 + threadIdx.x) * 4;
  if (i < n) {
    float4 v = *(const float4*)(s + i);
    d[i + 0] = __float2bfloat16(v.x);
    d[i + 1] = __float2bfloat16(v.y);
    d[i + 2] = __float2bfloat16(v.z);
    d[i + 3] = __float2bfloat16(v.w);
  }
}

// ---------------------------------------------------------------------------
// Causal EMA: s_t = 0.9 s_{t-1} + 0.1 x_t. 256-step lookback (0.9^256 ~ 2e-12).
// ---------------------------------------------------------------------------
__global__ __launch_bounds__(256)
void ema_kernel(const float* __restrict__ x, float* __restrict__ l2)
{
  const int b  = blockIdx.z;
  const int t0 = blockIdx.y * 128;
  const int d  = blockIdx.x * 256 + threadIdx.x;
  const float* xp = x  + (size_t)b * T_ * D_ + d;
  float*       lp = l2 + (size_t)b * T_ * D_ + d;
  float s = 0.f;
  int ts = t0 - 256; if (ts < 0) ts = 0;
  for (int t = ts; t < t0; ++t)
    s = 0.9f * s + 0.1f * xp[(size_t)t * D_];
  for (int t = t0; t < t0 + 128; ++t) {
    s = 0.9f * s + 0.1f * xp[(size_t)t * D_];
    lp[(size_t)t * D_] = s;
  }
}

// ---------------------------------------------------------------------------
// Router head: lam = softmax(hdn @ rw2^T + rb2). One wave per row.
// ---------------------------------------------------------------------------
__global__ __launch_bounds__(256)
void router_kernel(const float* __restrict__ hdn, const float* __restrict__ rw2,
                   const float* __restrict__ rb2, float* __restrict__ lam)
{
  const int lane = threadIdx.x & 63;
  const int w    = threadIdx.x >> 6;
  const int m    = blockIdx.x * 4 + w;
  const float* hp = hdn + (size_t)m * DR_;
  float s0 = 0.f, s1 = 0.f, s2 = 0.f;
  for (int k = lane * 4; k < DR_; k += 256) {
    float4 h4 = *(const float4*)(hp + k);
    float4 w0 = *(const float4*)(rw2 + k);
    float4 w1 = *(const float4*)(rw2 + DR_ + k);
    float4 w2 = *(const float4*)(rw2 + 2 * DR_ + k);
    s0 += h4.x * w0.x + h4.y * w0.y + h4.z * w0.z + h4.w * w0.w;
    s1 += h4.x * w1.x + h4.y * w1.y + h4.z * w1.z + h4.w * w1.w;
    s2 += h4.x * w2.x + h4.y * w2.y + h4.z * w2.z + h4.w * w2.w;
  }
  #pragma unroll
  for (int off = 32; off > 0; off >>= 1) {
    s0 += __shfl_down(s0, off);
    s1 += __shfl_down(s1, off);
    s2 += __shfl_down(s2, off);
  }
  if (lane == 0) {
    s0 += rb2[0]; s1 += rb2[1]; s2 += rb2[2];
    float mx = fmaxf(s0, fmaxf(s1, s2));
    float e0 = __expf(s0 - mx), e1 = __expf(s1 - mx), e2 = __expf(s2 - mx);
    float inv = 1.f / (e0 + e1 + e2);
    lam[(size_t)m * 3 + 0] = e0 * inv;
    lam[(size_t)m * 3 + 1] = e1 * inv;
    lam[(size_t)m * 3 + 2] = e2 * inv;
  }
}

// ---------------------------------------------------------------------------
// fused = lam0*x + lam1*l2 + lam2*l3mem  -> bf16 (feeds k/v GEMMs)
// ---------------------------------------------------------------------------
__global__ __launch_bounds__(256)
void fuse_bf16(const float* __restrict__ x, const float* __restrict__ l2,
               const float* __restrict__ l3m, const float* __restrict__ lam,
               __hip_bfloat16* __restrict__ fb)
{
  const int i4 = blockIdx.x * 256 + threadIdx.x;   // over M_*D_/4
  const int m  = i4 >> 9;                          // D_/4 = 512
  const int c  = (i4 & 511) << 2;
  const int b  = m >> 10;
  const float w0 = lam[m * 3 + 0], w1 = lam[m * 3 + 1], w2 = lam[m * 3 + 2];
  const float4 xv = *(const float4*)(x   + (size_t)m * D_ + c);
  const float4 ev = *(const float4*)(l2  + (size_t)m * D_ + c);
  const float4 gv = *(const float4*)(l3m + (size_t)b * D_ + c);
  __hip_bfloat16* o = fb + (size_t)m * D_ + c;
  o[0] = __float2bfloat16(w0 * xv.x + w1 * ev.x + w2 * gv.x);
  o[1] = __float2bfloat16(w0 * xv.y + w1 * ev.y + w2 * gv.y);
  o[2] = __float2bfloat16(w0 * xv.z + w1 * ev.z + w2 * gv.z);
  o[3] = __float2bfloat16(w0 * xv.w + w1 * ev.w + w2 * gv.w);
}

// ---------------------------------------------------------------------------
// Flash-style causal attention, fp32 math. Br=Bc=32, dh=128. 256 threads.
// q fp32 [b,t,d]; k/v fp32 heads layout [b,h,t,dh]; output bf16 [b,t,d].
// ---------------------------------------------------------------------------
__global__ __launch_bounds__(256)
void flash_attn(const float* __restrict__ qg, const float* __restrict__ kg,
                const float* __restrict__ vg, __hip_bfloat16* __restrict__ og)
{
  __shared__ float Qs[32][132];
  __shared__ float Ks[32][132];
  __shared__ float Vs[32][132];
  __shared__ float Ss[32][36];
  __shared__ float mrow[32], lrow[32], arow[32];
  const int tid = threadIdx.x;
  const int qt  = blockIdx.x;
  const int bh  = blockIdx.y;
  const int b   = bh >> 4, h = bh & 15;
  const int q0  = qt * 32;

  const float* qsrc = qg + ((size_t)b * T_) * D_ + (size_t)h * DH_;
  for (int i = tid; i < 32 * 32; i += 256) {
    int r = i >> 5, c4 = (i & 31) << 2;
    *(float4*)&Qs[r][c4] = *(const float4*)(qsrc + (size_t)(q0 + r) * D_ + c4);
  }
  if (tid < 32) { mrow[tid] = -INFINITY; lrow[tid] = 0.f; }

  float oacc[16];
  #pragma unroll
  for (int i = 0; i < 16; ++i) oacc[i] = 0.f;

  const float* kb = kg + (size_t)bh * T_ * DH_;
  const float* vb = vg + (size_t)bh * T_ * DH_;
  const int ty = tid >> 4, tx = tid & 15;
  const int orow = tid >> 3, ocg = (tid & 7) << 2;
  const float scale = 0.08838834764831845f;          // 1/sqrt(128)

  for (int kt = 0; kt <= qt; ++kt) {
    const int k0 = kt * 32;
    __syncthreads();
    for (int i = tid; i < 32 * 32; i += 256) {
      int r = i >> 5, c4 = (i & 31) << 2;
      *(float4*)&Ks[r][c4] = *(const float4*)(kb + (size_t)(k0 + r) * DH_ + c4);
      *(float4*)&Vs[r][c4] = *(const float4*)(vb + (size_t)(k0 + r) * DH_ + c4);
    }
    __syncthreads();

    float s00 = 0.f, s01 = 0.f, s10 = 0.f, s11 = 0.f;
    #pragma unroll
    for (int k = 0; k < DH_; k += 4) {
      float4 a0 = *(const float4*)&Qs[2 * ty][k];
      float4 a1 = *(const float4*)&Qs[2 * ty + 1][k];
      float4 b0 = *(const float4*)&Ks[2 * tx][k];
      float4 b1 = *(const float4*)&Ks[2 * tx + 1][k];
      s00 += a0.x * b0.x + a0.y * b0.y + a0.z * b0.z + a0.w * b0.w;
      s01 += a0.x * b1.x + a0.y * b1.y + a0.z * b1.z + a0.w * b1.w;
      s10 += a1.x * b0.x + a1.y * b0.y + a1.z * b0.z + a1.w * b0.w;
      s11 += a1.x * b1.x + a1.y * b1.y + a1.z * b1.z + a1.w * b1.w;
    }
    {
      const int gq0 = q0 + 2 * ty, gq1 = gq0 + 1;
      const int gk0 = k0 + 2 * tx, gk1 = gk0 + 1;
      Ss[2 * ty][2 * tx]         = (gk0 <= gq0) ? s00 * scale : -INFINITY;
      Ss[2 * ty][2 * tx + 1]     = (gk1 <= gq0) ? s01 * scale : -INFINITY;
      Ss[2 * ty + 1][2 * tx]     = (gk0 <= gq1) ? s10 * scale : -INFINITY;
      Ss[2 * ty + 1][2 * tx + 1] = (gk1 <= gq1) ? s11 * scale : -INFINITY;
    }
    __syncthreads();
    if (tid < 32) {
      float mo = mrow[tid], mx = mo;
      #pragma unroll
      for (int c = 0; c < 32; ++c) mx = fmaxf(mx, Ss[tid][c]);
      float alpha = __expf(mo - mx);
      float ls = 0.f;
      #pragma unroll
      for (int c = 0; c < 32; ++c) {
        float p = __expf(Ss[tid][c] - mx);
        Ss[tid][c] = p;
        ls += p;
      }
      mrow[tid] = mx;
      lrow[tid] = lrow[tid] * alpha + ls;
      arow[tid] = alpha;
    }
    __syncthreads();
    const float al = arow[orow];
    #pragma unroll
    for (int i = 0; i < 16; ++i) oacc[i] *= al;
    #pragma unroll 4
    for (int cc = 0; cc < 32; ++cc) {
      const float p = Ss[orow][cc];
      #pragma unroll
      for (int j = 0; j < 4; ++j) {
        float4 vv = *(const float4*)&Vs[cc][j * 32 + ocg];
        oacc[j * 4 + 0] += p * vv.x;
        oacc[j * 4 + 1] += p * vv.y;
        oacc[j * 4 + 2] += p * vv.z;
        oacc[j * 4 + 3] += p * vv.w;
      }
    }
  }

  const float inv = 1.f / lrow[orow];
  __hip_bfloat16* od = og + ((size_t)b * T_ + q0 + orow) * D_ + (size_t)h * DH_;
  #pragma unroll
  for (int j = 0; j < 4; ++j) {
    od[j * 32 + ocg + 0] = __float2bfloat16(oacc[j * 4 + 0] * inv);
    od[j * 32 + ocg + 1] = __float2bfloat16(oacc[j * 4 + 1] * inv);
    od[j * 32 + ocg + 2] = __float2bfloat16(oacc[j * 4 + 2] * inv);
    od[j * 32 + ocg + 3] = __float2bfloat16(oacc[j * 4 + 3] * inv);
  }
}

// ---------------------------------------------------------------------------
extern "C" void kernel_launch(void* const* d_in, const int* in_sizes, int n_in,
                              void* d_out, int out_size, void* d_ws, size_t ws_size,
                              hipStream_t stream)
{
  const float* x   = (const float*)d_in[0];
  const float* l3m = (const float*)d_in[1];
  const float* wq  = (const float*)d_in[2];
  const float* wk  = (const float*)d_in[3];
  const float* wv  = (const float*)d_in[4];
  const float* wo  = (const float*)d_in[5];
  const float* rw1 = (const float*)d_in[6];
  const float* rb1 = (const float*)d_in[7];
  const float* rw2 = (const float*)d_in[8];
  const float* rb2 = (const float*)d_in[9];

  float* out = (float*)d_out;                 // [b,t,d]      4,194,304 f32
  float* kh  = out + 4194304;                 // [b,h,t,dh]   4,194,304 f32
  float* vh  = out + 8388608;                 // [b,h,t,dh]   4,194,304 f32
  float* lam = out + 12582912;                // [b,t,3]          6,144 f32

  // ws layout (80 MB):
  char* wsb = (char*)d_ws;
  float*          q_f32  = (float*)(wsb);                        // 16 MB
  float*          l2_f32 = (float*)(wsb + (16u << 20));          // 16 MB
  float*          hdn    = (float*)(wsb + (32u << 20));          //  8 MB
  __hip_bfloat16* wkb    = (__hip_bfloat16*)(wsb + (40u << 20)); //  8 MB
  __hip_bfloat16* wvb    = (__hip_bfloat16*)(wsb + (48u << 20)); //  8 MB
  __hip_bfloat16* wob    = (__hip_bfloat16*)(wsb + (56u << 20)); //  8 MB
  __hip_bfloat16* fusedb = (__hip_bfloat16*)(wsb + (64u << 20)); //  8 MB
  __hip_bfloat16* attnb  = (__hip_bfloat16*)(wsb + (72u << 20)); //  8 MB
  // d_out scratch reuse (regions written later in the call, sequential stream):
  __hip_bfloat16* wqb  = (__hip_bfloat16*)kh;                    // 8 MB (kh written step 7)
  __hip_bfloat16* rw1b = (__hip_bfloat16*)kh + 4194304;          // 4 MB
  __hip_bfloat16* xb   = (__hip_bfloat16*)vh;                    // 8 MB (vh written step 8)
  __hip_bfloat16* qb   = (__hip_bfloat16*)vh + 4194304;          // 8 MB

  dim3 blk(256);

  // 1. fp32->bf16: x, wq, wk, wv, wo, rw1
  cvt6<<<dim3(4096, 6), blk, 0, stream>>>(x, wq, wk, wv, wo, rw1,
                                          xb, wqb, wkb, wvb, wob, rw1b,
                                          M_ * D_, D_ * D_, D_ * D_, D_ * D_, D_ * D_, DR_ * D_);
  // 2. q = x @ wq^T  (fp32 for flash_attn + bf16 for router GEMM)
  gemm_mfma<0, false, true><<<dim3(16, 16), blk, 0, stream>>>(xb, wqb, nullptr, q_f32, qb, M_, D_, D_);
  // 3. l2 = causal EMA(x)
  ema_kernel<<<dim3(8, 8, 2), blk, 0, stream>>>(x, l2_f32);
  // 4. hdn = silu(q @ rw1^T + rb1)
  gemm_mfma<0, true, false><<<dim3(8, 16), blk, 0, stream>>>(qb, rw1b, rb1, hdn, nullptr, M_, DR_, D_);
  // 5. lam = softmax(hdn @ rw2^T + rb2)
  router_kernel<<<dim3(512), blk, 0, stream>>>(hdn, rw2, rb2, lam);
  // 6. fused = lam0*x + lam1*l2 + lam2*l3  -> bf16
  fuse_bf16<<<dim3(4096), blk, 0, stream>>>(x, l2_f32, l3m, lam, fusedb);
  // 7/8. kh, vh (heads-layout fp32 into d_out; overwrites wqb/rw1b then xb/qb)
  gemm_mfma<1, false, false><<<dim3(16, 16), blk, 0, stream>>>(fusedb, wkb, nullptr, kh, nullptr, M_, D_, D_);
  gemm_mfma<1, false, false><<<dim3(16, 16), blk, 0, stream>>>(fusedb, wvb, nullptr, vh, nullptr, M_, D_, D_);
  // 9. causal flash attention -> bf16 attnb
  flash_attn<<<dim3(32, 32), blk, 0, stream>>>(q_f32, kh, vh, attnb);
  // 10. out = attn @ wo^T
  gemm_mfma<0, false, false><<<dim3(16, 16), blk, 0, stream>>>(attnb, wob, nullptr, out, nullptr, M_, D_, D_);
}

// Round 4
// 523.379 us; speedup vs baseline: 3.9730x; 1.8458x over previous
//
#include <hip/hip_runtime.h>
#include <hip/hip_bf16.h>
#include <math.h>

#define B_  2
#define T_  1024
#define D_  2048
#define H_  16
#define DH_ 128
#define M_  2048          // B_*T_
#define DR_ 1024          // D_/2

typedef __attribute__((ext_vector_type(8))) short short8;
typedef __attribute__((ext_vector_type(4))) short sh4;
typedef __attribute__((ext_vector_type(4))) float f32x4;

// async global->LDS, 16B per lane, dest = wave-uniform base + lane*16
__device__ __forceinline__ void gld16(const __hip_bfloat16* g, __hip_bfloat16* l) {
  __builtin_amdgcn_global_load_lds(
      (const __attribute__((address_space(1))) unsigned int*)g,
      (__attribute__((address_space(3))) unsigned int*)l, 16, 0, 0);
}

// ---------------------------------------------------------------------------
// bf16 MFMA GEMM: C = act(A * B^T + bias). A:[M,K] bf16 rm, B:[N,K] bf16 rm.
// 128x128 tile, BK=32, 256 threads (4 waves in 2x2), 4x4 16x16x32 MFMA/wave.
// CMODE 0: C fp32 [M,N].
// CMODE 1: Cb bf16 [M,N] only.
// CMODE 2: C fp32 heads [b,h,t,dh] + Cb bf16 heads [b,h,t,dh].
// CMODE 3: C fp32 heads [b,h,t,dh] + Cb bf16 transposed [b,h,dh,t].
// ---------------------------------------------------------------------------
template<int CMODE, bool SILU>
__global__ __launch_bounds__(256)
void gemm_mfma(const __hip_bfloat16* __restrict__ A,
               const __hip_bfloat16* __restrict__ Bm,
               const float* __restrict__ bias,
               float* __restrict__ C, __hip_bfloat16* __restrict__ Cb,
               int M, int N, int K)
{
  __shared__ __hip_bfloat16 As[128 * 32];
  __shared__ __hip_bfloat16 Bs[128 * 32];
  const int tid  = threadIdx.x;
  const int wave = tid >> 6;
  const int lane = tid & 63;
  const int m0 = blockIdx.y * 128;
  const int n0 = blockIdx.x * 128;
  const int wm = (wave >> 1) * 64;   // wave's 64-row half
  const int wn = (wave & 1) * 64;    // wave's 64-col half

  const int srow = lane >> 2;          // 0..15 row within 16-row group
  const int scol = (lane & 3) * 8;     // bf16 element offset in k
  const __hip_bfloat16* Ag = A  + (size_t)(m0 + wave * 32 + srow) * K + scol;
  const __hip_bfloat16* Bg = Bm + (size_t)(n0 + wave * 32 + srow) * K + scol;
  __hip_bfloat16* Al0 = As + (wave * 2 + 0) * 512;
  __hip_bfloat16* Al1 = As + (wave * 2 + 1) * 512;
  __hip_bfloat16* Bl0 = Bs + (wave * 2 + 0) * 512;
  __hip_bfloat16* Bl1 = Bs + (wave * 2 + 1) * 512;

  const int fr = lane & 15;            // fragment row (m/n index)
  const int fk = (lane >> 4) * 8;      // fragment k offset

  f32x4 acc[4][4];
  #pragma unroll
  for (int i = 0; i < 4; ++i)
    #pragma unroll
    for (int j = 0; j < 4; ++j) acc[i][j] = (f32x4)0.f;

  for (int k0 = 0; k0 < K; k0 += 32) {
    __syncthreads();
    gld16(Ag + k0,                  Al0);
    gld16(Ag + (size_t)16 * K + k0, Al1);
    gld16(Bg + k0,                  Bl0);
    gld16(Bg + (size_t)16 * K + k0, Bl1);
    __syncthreads();

    short8 af[4], bfr[4];
    #pragma unroll
    for (int i = 0; i < 4; ++i) {
      af[i]  = *(const short8*)(As + (wm + i * 16 + fr) * 32 + fk);
      bfr[i] = *(const short8*)(Bs + (wn + i * 16 + fr) * 32 + fk);
    }
    #pragma unroll
    for (int i = 0; i < 4; ++i)
      #pragma unroll
      for (int j = 0; j < 4; ++j)
        acc[i][j] = __builtin_amdgcn_mfma_f32_16x16x32_bf16(af[i], bfr[j], acc[i][j], 0, 0, 0);
  }

  // C/D layout (m89-verified): col = lane&15, row = (lane>>4)*4 + reg
  #pragma unroll
  for (int i = 0; i < 4; ++i) {
    #pragma unroll
    for (int j = 0; j < 4; ++j) {
      const int row0 = m0 + wm + i * 16 + (lane >> 4) * 4;
      const int col  = n0 + wn + j * 16 + (lane & 15);
      float vr[4];
      #pragma unroll
      for (int r = 0; r < 4; ++r) {
        float v = acc[i][j][r];
        if (bias) v += bias[col];
        if (SILU) v = v / (1.f + __expf(-v));
        vr[r] = v;
      }
      if (CMODE == 0) {
        #pragma unroll
        for (int r = 0; r < 4; ++r) C[(size_t)(row0 + r) * N + col] = vr[r];
      } else if (CMODE == 1) {
        #pragma unroll
        for (int r = 0; r < 4; ++r) Cb[(size_t)(row0 + r) * N + col] = __float2bfloat16(vr[r]);
      } else {
        const int bb = row0 >> 10, t0v = row0 & 1023;   // row = b*T + t
        const int hh = col >> 7,  dd = col & 127;       // col = h*DH + dd
        #pragma unroll
        for (int r = 0; r < 4; ++r)
          C[(((size_t)(bb * H_ + hh)) * T_ + t0v + r) * DH_ + dd] = vr[r];
        if (CMODE == 2) {
          #pragma unroll
          for (int r = 0; r < 4; ++r)
            Cb[(((size_t)(bb * H_ + hh)) * T_ + t0v + r) * DH_ + dd] = __float2bfloat16(vr[r]);
        } else {  // CMODE 3: transposed [b,h,dh,t], 4 consecutive t packed
          __hip_bfloat16 tmp[4];
          #pragma unroll
          for (int r = 0; r < 4; ++r) tmp[r] = __float2bfloat16(vr[r]);
          *(sh4*)(Cb + (((size_t)(bb * H_ + hh)) * DH_ + dd) * T_ + t0v) = *(const sh4*)tmp;
        }
      }
    }
  }
}

// ---------------------------------------------------------------------------
// fp32 -> bf16 conversions for x, wq, wk, wv, wo, rw1 in one launch.
// ---------------------------------------------------------------------------
__global__ __launch_bounds__(256)
void cvt6(const float* __restrict__ s0, const float* __restrict__ s1,
          const float* __restrict__ s2, const float* __restrict__ s3,
          const float* __restrict__ s4, const float* __restrict__ s5,
          __hip_bfloat16* d0, __hip_bfloat16* d1, __hip_bfloat16* d2,
          __hip_bfloat16* d3, __hip_bfloat16* d4, __hip_bfloat16* d5,
          int n0, int n1, int n2, int n3, int n4, int n5)
{
  const float* s; __hip_bfloat16* d; int n;
  switch (blockIdx.y) {
    case 0: s = s0; d = d0; n = n0; break;
    case 1: s = s1; d = d1; n = n1; break;
    case 2: s = s2; d = d2; n = n2; break;
    case 3: s = s3; d = d3; n = n3; break;
    case 4: s = s4; d = d4; n = n4; break;
    default: s = s5; d = d5; n = n5; break;
  }
  const int i = (blockIdx.x * 256 + threadIdx.x) * 4;
  if (i < n) {
    float4 v = *(const float4*)(s + i);
    d[i + 0] = __float2bfloat16(v.x);
    d[i + 1] = __float2bfloat16(v.y);
    d[i + 2] = __float2bfloat16(v.z);
    d[i + 3] = __float2bfloat16(v.w);
  }
}

// ---------------------------------------------------------------------------
// Causal EMA: s_t = 0.9 s_{t-1} + 0.1 x_t. 256-step lookback (0.9^256 ~ 2e-12).
// ---------------------------------------------------------------------------
__global__ __launch_bounds__(256)
void ema_kernel(const float* __restrict__ x, float* __restrict__ l2)
{
  const int b  = blockIdx.z;
  const int t0 = blockIdx.y * 128;
  const int d  = blockIdx.x * 256 + threadIdx.x;
  const float* xp = x  + (size_t)b * T_ * D_ + d;
  float*       lp = l2 + (size_t)b * T_ * D_ + d;
  float s = 0.f;
  int ts = t0 - 256; if (ts < 0) ts = 0;
  for (int t = ts; t < t0; ++t)
    s = 0.9f * s + 0.1f * xp[(size_t)t * D_];
  for (int t = t0; t < t0 + 128; ++t) {
    s = 0.9f * s + 0.1f * xp[(size_t)t * D_];
    lp[(size_t)t * D_] = s;
  }
}

// ---------------------------------------------------------------------------
// Router head: lam = softmax(hdn @ rw2^T + rb2). One wave per row.
// ---------------------------------------------------------------------------
__global__ __launch_bounds__(256)
void router_kernel(const float* __restrict__ hdn, const float* __restrict__ rw2,
                   const float* __restrict__ rb2, float* __restrict__ lam)
{
  const int lane = threadIdx.x & 63;
  const int w    = threadIdx.x >> 6;
  const int m    = blockIdx.x * 4 + w;
  const float* hp = hdn + (size_t)m * DR_;
  float s0 = 0.f, s1 = 0.f, s2 = 0.f;
  for (int k = lane * 4; k < DR_; k += 256) {
    float4 h4 = *(const float4*)(hp + k);
    float4 w0 = *(const float4*)(rw2 + k);
    float4 w1 = *(const float4*)(rw2 + DR_ + k);
    float4 w2 = *(const float4*)(rw2 + 2 * DR_ + k);
    s0 += h4.x * w0.x + h4.y * w0.y + h4.z * w0.z + h4.w * w0.w;
    s1 += h4.x * w1.x + h4.y * w1.y + h4.z * w1.z + h4.w * w1.w;
    s2 += h4.x * w2.x + h4.y * w2.y + h4.z * w2.z + h4.w * w2.w;
  }
  #pragma unroll
  for (int off = 32; off > 0; off >>= 1) {
    s0 += __shfl_down(s0, off);
    s1 += __shfl_down(s1, off);
    s2 += __shfl_down(s2, off);
  }
  if (lane == 0) {
    s0 += rb2[0]; s1 += rb2[1]; s2 += rb2[2];
    float mx = fmaxf(s0, fmaxf(s1, s2));
    float e0 = __expf(s0 - mx), e1 = __expf(s1 - mx), e2 = __expf(s2 - mx);
    float inv = 1.f / (e0 + e1 + e2);
    lam[(size_t)m * 3 + 0] = e0 * inv;
    lam[(size_t)m * 3 + 1] = e1 * inv;
    lam[(size_t)m * 3 + 2] = e2 * inv;
  }
}

// ---------------------------------------------------------------------------
// fused = lam0*x + lam1*l2 + lam2*l3mem  -> bf16 (feeds k/v GEMMs)
// ---------------------------------------------------------------------------
__global__ __launch_bounds__(256)
void fuse_bf16(const float* __restrict__ x, const float* __restrict__ l2,
               const float* __restrict__ l3m, const float* __restrict__ lam,
               __hip_bfloat16* __restrict__ fb)
{
  const int i4 = blockIdx.x * 256 + threadIdx.x;   // over M_*D_/4
  const int m  = i4 >> 9;                          // D_/4 = 512
  const int c  = (i4 & 511) << 2;
  const int b  = m >> 10;
  const float w0 = lam[m * 3 + 0], w1 = lam[m * 3 + 1], w2 = lam[m * 3 + 2];
  const float4 xv = *(const float4*)(x   + (size_t)m * D_ + c);
  const float4 ev = *(const float4*)(l2  + (size_t)m * D_ + c);
  const float4 gv = *(const float4*)(l3m + (size_t)b * D_ + c);
  __hip_bfloat16* o = fb + (size_t)m * D_ + c;
  o[0] = __float2bfloat16(w0 * xv.x + w1 * ev.x + w2 * gv.x);
  o[1] = __float2bfloat16(w0 * xv.y + w1 * ev.y + w2 * gv.y);
  o[2] = __float2bfloat16(w0 * xv.z + w1 * ev.z + w2 * gv.z);
  o[3] = __float2bfloat16(w0 * xv.w + w1 * ev.w + w2 * gv.w);
}

// ---------------------------------------------------------------------------
// MFMA flash attention. 64-row Q-tile per block, 4 waves x 16 q-rows,
// 64-key K-tiles, 16x16x32 bf16 MFMA for QK^T and PV.
// qg: bf16 [M,D] row-major; kg: bf16 [b,h,t,dh]; vg: bf16 [b,h,dh,t] (pre-T);
// og: bf16 [b,t,d].
// LDS rows padded +8 elems (16B) so ds_read_b128 spreads banks evenly.
// ---------------------------------------------------------------------------
__global__ __launch_bounds__(256)
void flash_mfma(const __hip_bfloat16* __restrict__ qg,
                const __hip_bfloat16* __restrict__ kg,
                const __hip_bfloat16* __restrict__ vg,
                __hip_bfloat16* __restrict__ og)
{
  __shared__ __hip_bfloat16 Qs[64 * 136];
  __shared__ __hip_bfloat16 Ks[64 * 136];
  __shared__ __hip_bfloat16 Vt[128 * 72];
  __shared__ __hip_bfloat16 Ps[64 * 72];
  const int tid  = threadIdx.x;
  const int wave = tid >> 6, lane = tid & 63;
  const int qt = blockIdx.x, bh = blockIdx.y;
  const int b = bh >> 4, h = bh & 15;
  const int q0 = qt * 64;
  const int lo = lane & 15, hi = lane >> 4;

  // stage Q tile (64 rows x 128, row slice of qg)
  {
    const __hip_bfloat16* qsrc = qg + (size_t)(b * T_ + q0) * D_ + h * DH_;
    #pragma unroll
    for (int i = 0; i < 4; ++i) {
      const int ci = tid + 256 * i;              // chunk 0..1023
      const int r = ci >> 4, j = ci & 15;
      short8 v = *(const short8*)(qsrc + (size_t)r * D_ + j * 8);
      *(short8*)&Qs[r * 136 + j * 8] = v;
    }
  }
  __syncthreads();
  // hoist Q A-frags (loop-invariant)
  short8 aq[4];
  #pragma unroll
  for (int kk = 0; kk < 4; ++kk)
    aq[kk] = *(const short8*)&Qs[(wave * 16 + lo) * 136 + kk * 32 + hi * 8];

  f32x4 oacc[8];
  #pragma unroll
  for (int i = 0; i < 8; ++i) oacc[i] = (f32x4)0.f;
  float mrow[4] = {-INFINITY, -INFINITY, -INFINITY, -INFINITY};
  float lrow[4] = {0.f, 0.f, 0.f, 0.f};

  const __hip_bfloat16* kbp = kg + (size_t)bh * T_ * DH_;
  const __hip_bfloat16* vbp = vg + (size_t)bh * DH_ * T_;
  const float scale = 0.08838834764831845f;      // 1/sqrt(128)

  for (int kt = 0; kt <= qt; ++kt) {
    const int k0 = kt * 64;
    __syncthreads();   // prior iter's Ks/Vt reads complete
    #pragma unroll
    for (int i = 0; i < 4; ++i) {
      const int ci = tid + 256 * i;
      const int r = ci >> 4, j = ci & 15;        // K: 64 rows x 16 chunks
      short8 v = *(const short8*)(kbp + (size_t)(k0 + r) * DH_ + j * 8);
      *(short8*)&Ks[r * 136 + j * 8] = v;
      const int dd = ci >> 3, j2 = ci & 7;       // Vt: 128 rows x 8 chunks
      short8 w = *(const short8*)(vbp + (size_t)dd * T_ + k0 + j2 * 8);
      *(short8*)&Vt[dd * 72 + j2 * 8] = w;
    }
    __syncthreads();

    // S[16x64] = Q[16x128] K[64x128]^T
    f32x4 sc[4];
    #pragma unroll
    for (int nt = 0; nt < 4; ++nt) {
      sc[nt] = (f32x4)0.f;
      #pragma unroll
      for (int kk = 0; kk < 4; ++kk) {
        short8 bk = *(const short8*)&Ks[(nt * 16 + lo) * 136 + kk * 32 + hi * 8];
        sc[nt] = __builtin_amdgcn_mfma_f32_16x16x32_bf16(aq[kk], bk, sc[nt], 0, 0, 0);
      }
    }
    // scale + causal mask (row = q0+wave*16+hi*4+r, col = k0+nt*16+lo)
    const int qrow = q0 + wave * 16 + hi * 4;
    #pragma unroll
    for (int nt = 0; nt < 4; ++nt) {
      const int key = k0 + nt * 16 + lo;
      #pragma unroll
      for (int r = 0; r < 4; ++r) {
        float v = sc[nt][r] * scale;
        sc[nt][r] = (key <= qrow + r) ? v : -1e30f;
      }
    }
    // online softmax (row-wise over 16-lane column group)
    float alpha[4];
    #pragma unroll
    for (int r = 0; r < 4; ++r) {
      float mx = fmaxf(fmaxf(sc[0][r], sc[1][r]), fmaxf(sc[2][r], sc[3][r]));
      mx = fmaxf(mx, __shfl_xor(mx, 1));
      mx = fmaxf(mx, __shfl_xor(mx, 2));
      mx = fmaxf(mx, __shfl_xor(mx, 4));
      mx = fmaxf(mx, __shfl_xor(mx, 8));
      const float nm = fmaxf(mrow[r], mx);
      alpha[r] = __expf(mrow[r] - nm);
      mrow[r] = nm;
      float ls = 0.f;
      #pragma unroll
      for (int nt = 0; nt < 4; ++nt) {
        float p = __expf(sc[nt][r] - nm);
        sc[nt][r] = p;
        ls += p;
      }
      ls += __shfl_xor(ls, 1);
      ls += __shfl_xor(ls, 2);
      ls += __shfl_xor(ls, 4);
      ls += __shfl_xor(ls, 8);
      lrow[r] = lrow[r] * alpha[r] + ls;
    }
    // P (C-layout) -> LDS (wave-private region) as bf16
    #pragma unroll
    for (int nt = 0; nt < 4; ++nt)
      #pragma unroll
      for (int r = 0; r < 4; ++r)
        Ps[(wave * 16 + hi * 4 + r) * 72 + nt * 16 + lo] = __float2bfloat16(sc[nt][r]);
    // rescale O
    #pragma unroll
    for (int n2 = 0; n2 < 8; ++n2)
      #pragma unroll
      for (int r = 0; r < 4; ++r) oacc[n2][r] *= alpha[r];
    // O[16x128] += P[16x64] V[64x128]   (A = P from LDS, B = Vt)
    short8 ap[2];
    #pragma unroll
    for (int k2 = 0; k2 < 2; ++k2)
      ap[k2] = *(const short8*)&Ps[(wave * 16 + lo) * 72 + k2 * 32 + hi * 8];
    #pragma unroll
    for (int n2 = 0; n2 < 8; ++n2) {
      #pragma unroll
      for (int k2 = 0; k2 < 2; ++k2) {
        short8 bv = *(const short8*)&Vt[(n2 * 16 + lo) * 72 + k2 * 32 + hi * 8];
        oacc[n2] = __builtin_amdgcn_mfma_f32_16x16x32_bf16(ap[k2], bv, oacc[n2], 0, 0, 0);
      }
    }
  }

  // epilogue: O/l -> og [b,t,d]
  float inv[4];
  #pragma unroll
  for (int r = 0; r < 4; ++r) inv[r] = 1.f / lrow[r];
  __hip_bfloat16* od = og + (size_t)(b * T_ + q0 + wave * 16 + hi * 4) * D_ + h * DH_;
  #pragma unroll
  for (int n2 = 0; n2 < 8; ++n2)
    #pragma unroll
    for (int r = 0; r < 4; ++r)
      od[(size_t)r * D_ + n2 * 16 + lo] = __float2bfloat16(oacc[n2][r] * inv[r]);
}

// ---------------------------------------------------------------------------
extern "C" void kernel_launch(void* const* d_in, const int* in_sizes, int n_in,
                              void* d_out, int out_size, void* d_ws, size_t ws_size,
                              hipStream_t stream)
{
  const float* x   = (const float*)d_in[0];
  const float* l3m = (const float*)d_in[1];
  const float* wq  = (const float*)d_in[2];
  const float* wk  = (const float*)d_in[3];
  const float* wv  = (const float*)d_in[4];
  const float* wo  = (const float*)d_in[5];
  const float* rw1 = (const float*)d_in[6];
  const float* rb1 = (const float*)d_in[7];
  const float* rw2 = (const float*)d_in[8];
  const float* rb2 = (const float*)d_in[9];

  float* out = (float*)d_out;                 // [b,t,d]      4,194,304 f32
  float* kh  = out + 4194304;                 // [b,h,t,dh]   4,194,304 f32
  float* vh  = out + 8388608;                 // [b,h,t,dh]   4,194,304 f32
  float* lam = out + 12582912;                // [b,t,3]          6,144 f32

  // ws layout (80 MB):
  char* wsb = (char*)d_ws;
  float*          l2_f32 = (float*)(wsb);                        // 16 MB
  float*          hdn    = (float*)(wsb + (16u << 20));          //  8 MB
  __hip_bfloat16* wkb    = (__hip_bfloat16*)(wsb + (24u << 20)); //  8 MB
  __hip_bfloat16* wvb    = (__hip_bfloat16*)(wsb + (32u << 20)); //  8 MB
  __hip_bfloat16* wob    = (__hip_bfloat16*)(wsb + (40u << 20)); //  8 MB
  __hip_bfloat16* fusedb = (__hip_bfloat16*)(wsb + (48u << 20)); //  8 MB
  __hip_bfloat16* attnb  = (__hip_bfloat16*)(wsb + (56u << 20)); //  8 MB
  __hip_bfloat16* khb    = (__hip_bfloat16*)(wsb + (64u << 20)); //  8 MB bf16 heads
  __hip_bfloat16* vtb    = (__hip_bfloat16*)(wsb + (72u << 20)); //  8 MB bf16 [b,h,dh,t]
  // d_out scratch reuse (regions written later in the stream order):
  __hip_bfloat16* wqb  = (__hip_bfloat16*)kh;                    // 8 MB (kh written step 7)
  __hip_bfloat16* rw1b = (__hip_bfloat16*)kh + 4194304;          // 4 MB (read step 4 < 7)
  __hip_bfloat16* xb   = (__hip_bfloat16*)vh;                    // 8 MB (vh written step 8)
  __hip_bfloat16* qb   = (__hip_bfloat16*)out;                   // 8 MB (out written step 10; qb read 4 & 9)

  dim3 blk(256);

  // 1. fp32->bf16: x, wq, wk, wv, wo, rw1
  cvt6<<<dim3(4096, 6), blk, 0, stream>>>(x, wq, wk, wv, wo, rw1,
                                          xb, wqb, wkb, wvb, wob, rw1b,
                                          M_ * D_, D_ * D_, D_ * D_, D_ * D_, D_ * D_, DR_ * D_);
  // 2. qb = bf16(x @ wq^T)   (row-major bf16 only)
  gemm_mfma<1, false><<<dim3(16, 16), blk, 0, stream>>>(xb, wqb, nullptr, nullptr, qb, M_, D_, D_);
  // 3. l2 = causal EMA(x)
  ema_kernel<<<dim3(8, 8, 2), blk, 0, stream>>>(x, l2_f32);
  // 4. hdn = silu(q @ rw1^T + rb1)
  gemm_mfma<0, true><<<dim3(8, 16), blk, 0, stream>>>(qb, rw1b, rb1, hdn, nullptr, M_, DR_, D_);
  // 5. lam = softmax(hdn @ rw2^T + rb2)
  router_kernel<<<dim3(512), blk, 0, stream>>>(hdn, rw2, rb2, lam);
  // 6. fused = lam0*x + lam1*l2 + lam2*l3  -> bf16
  fuse_bf16<<<dim3(4096), blk, 0, stream>>>(x, l2_f32, l3m, lam, fusedb);
  // 7. kh fp32 heads + khb bf16 heads
  gemm_mfma<2, false><<<dim3(16, 16), blk, 0, stream>>>(fusedb, wkb, nullptr, kh, khb, M_, D_, D_);
  // 8. vh fp32 heads + vtb bf16 transposed heads
  gemm_mfma<3, false><<<dim3(16, 16), blk, 0, stream>>>(fusedb, wvb, nullptr, vh, vtb, M_, D_, D_);
  // 9. MFMA flash attention -> bf16 attnb [b,t,d]
  flash_mfma<<<dim3(16, 32), blk, 0, stream>>>(qb, khb, vtb, attnb);
  // 10. out = attn @ wo^T
  gemm_mfma<0, false><<<dim3(16, 16), blk, 0, stream>>>(attnb, wob, nullptr, out, nullptr, M_, D_, D_);
}

// Round 5
// 431.372 us; speedup vs baseline: 4.8204x; 1.2133x over previous
//
#include <hip/hip_runtime.h>
#include <hip/hip_bf16.h>
#include <math.h>

#define B_  2
#define T_  1024
#define D_  2048
#define H_  16
#define DH_ 128
#define M_  2048          // B_*T_
#define DR_ 1024          // D_/2

typedef __attribute__((ext_vector_type(8))) short short8;
typedef __attribute__((ext_vector_type(4))) short sh4;
typedef __attribute__((ext_vector_type(4))) float f32x4;

// async global->LDS, 16B per lane, dest = wave-uniform base + lane*16
__device__ __forceinline__ void gld16(const __hip_bfloat16* g, __hip_bfloat16* l) {
  __builtin_amdgcn_global_load_lds(
      (const __attribute__((address_space(1))) unsigned int*)g,
      (__attribute__((address_space(3))) unsigned int*)l, 16, 0, 0);
}

// ---------------------------------------------------------------------------
// bf16 MFMA GEMM: C = act(A * B^T + bias). A:[M,K] bf16 rm, B:[N,K] bf16 rm.
// 128x128 tile, BK=32, 256 threads (4 waves in 2x2), 4x4 16x16x32 MFMA/wave.
// CMODE 0: C fp32 [M,N].
// CMODE 1: Cb bf16 [M,N] only.
// CMODE 4: merged KV. col<2048: C fp32 heads + Cb bf16 heads (k).
//          col>=2048: C2 fp32 heads + Cb2 bf16 transposed [b,h,dh,t] (v).
// ---------------------------------------------------------------------------
template<int CMODE, bool SILU>
__global__ __launch_bounds__(256)
void gemm_mfma(const __hip_bfloat16* __restrict__ A,
               const __hip_bfloat16* __restrict__ Bm,
               const float* __restrict__ bias,
               float* __restrict__ C, __hip_bfloat16* __restrict__ Cb,
               float* __restrict__ C2, __hip_bfloat16* __restrict__ Cb2,
               int M, int N, int K)
{
  __shared__ __hip_bfloat16 As[128 * 32];
  __shared__ __hip_bfloat16 Bs[128 * 32];
  const int tid  = threadIdx.x;
  const int wave = tid >> 6;
  const int lane = tid & 63;
  const int m0 = blockIdx.y * 128;
  const int n0 = blockIdx.x * 128;
  const int wm = (wave >> 1) * 64;   // wave's 64-row half
  const int wn = (wave & 1) * 64;    // wave's 64-col half

  const int srow = lane >> 2;          // 0..15 row within 16-row group
  const int scol = (lane & 3) * 8;     // bf16 element offset in k
  const __hip_bfloat16* Ag = A  + (size_t)(m0 + wave * 32 + srow) * K + scol;
  const __hip_bfloat16* Bg = Bm + (size_t)(n0 + wave * 32 + srow) * K + scol;
  __hip_bfloat16* Al0 = As + (wave * 2 + 0) * 512;
  __hip_bfloat16* Al1 = As + (wave * 2 + 1) * 512;
  __hip_bfloat16* Bl0 = Bs + (wave * 2 + 0) * 512;
  __hip_bfloat16* Bl1 = Bs + (wave * 2 + 1) * 512;

  const int fr = lane & 15;            // fragment row (m/n index)
  const int fk = (lane >> 4) * 8;      // fragment k offset

  f32x4 acc[4][4];
  #pragma unroll
  for (int i = 0; i < 4; ++i)
    #pragma unroll
    for (int j = 0; j < 4; ++j) acc[i][j] = (f32x4)0.f;

  for (int k0 = 0; k0 < K; k0 += 32) {
    __syncthreads();
    gld16(Ag + k0,                  Al0);
    gld16(Ag + (size_t)16 * K + k0, Al1);
    gld16(Bg + k0,                  Bl0);
    gld16(Bg + (size_t)16 * K + k0, Bl1);
    __syncthreads();

    short8 af[4], bfr[4];
    #pragma unroll
    for (int i = 0; i < 4; ++i) {
      af[i]  = *(const short8*)(As + (wm + i * 16 + fr) * 32 + fk);
      bfr[i] = *(const short8*)(Bs + (wn + i * 16 + fr) * 32 + fk);
    }
    #pragma unroll
    for (int i = 0; i < 4; ++i)
      #pragma unroll
      for (int j = 0; j < 4; ++j)
        acc[i][j] = __builtin_amdgcn_mfma_f32_16x16x32_bf16(af[i], bfr[j], acc[i][j], 0, 0, 0);
  }

  // C/D layout (m89-verified): col = lane&15, row = (lane>>4)*4 + reg
  #pragma unroll
  for (int i = 0; i < 4; ++i) {
    #pragma unroll
    for (int j = 0; j < 4; ++j) {
      const int row0 = m0 + wm + i * 16 + (lane >> 4) * 4;
      const int col  = n0 + wn + j * 16 + (lane & 15);
      float vr[4];
      #pragma unroll
      for (int r = 0; r < 4; ++r) {
        float v = acc[i][j][r];
        if (bias) v += bias[col];
        if (SILU) v = v / (1.f + __expf(-v));
        vr[r] = v;
      }
      if (CMODE == 0) {
        #pragma unroll
        for (int r = 0; r < 4; ++r) C[(size_t)(row0 + r) * N + col] = vr[r];
      } else if (CMODE == 1) {
        #pragma unroll
        for (int r = 0; r < 4; ++r) Cb[(size_t)(row0 + r) * N + col] = __float2bfloat16(vr[r]);
      } else {  // CMODE 4
        const int bb = row0 >> 10, t0v = row0 & 1023;   // row = b*T + t
        if (col < D_) {                                  // K head
          const int hh = col >> 7, dd = col & 127;
          #pragma unroll
          for (int r = 0; r < 4; ++r) {
            const size_t idx = (((size_t)(bb * H_ + hh)) * T_ + t0v + r) * DH_ + dd;
            C[idx] = vr[r];
            Cb[idx] = __float2bfloat16(vr[r]);
          }
        } else {                                         // V head (+ transposed bf16)
          const int c2 = col - D_;
          const int hh = c2 >> 7, dd = c2 & 127;
          #pragma unroll
          for (int r = 0; r < 4; ++r)
            C2[(((size_t)(bb * H_ + hh)) * T_ + t0v + r) * DH_ + dd] = vr[r];
          __hip_bfloat16 tmp[4];
          #pragma unroll
          for (int r = 0; r < 4; ++r) tmp[r] = __float2bfloat16(vr[r]);
          *(sh4*)(Cb2 + (((size_t)(bb * H_ + hh)) * DH_ + dd) * T_ + t0v) = *(const sh4*)tmp;
        }
      }
    }
  }
}

// ---------------------------------------------------------------------------
// fp32 -> bf16 conversions for x, wq, wk, wv, wo, rw1 in one launch.
// ---------------------------------------------------------------------------
__global__ __launch_bounds__(256)
void cvt6(const float* __restrict__ s0, const float* __restrict__ s1,
          const float* __restrict__ s2, const float* __restrict__ s3,
          const float* __restrict__ s4, const float* __restrict__ s5,
          __hip_bfloat16* d0, __hip_bfloat16* d1, __hip_bfloat16* d2,
          __hip_bfloat16* d3, __hip_bfloat16* d4, __hip_bfloat16* d5,
          int n0, int n1, int n2, int n3, int n4, int n5)
{
  const float* s; __hip_bfloat16* d; int n;
  switch (blockIdx.y) {
    case 0: s = s0; d = d0; n = n0; break;
    case 1: s = s1; d = d1; n = n1; break;
    case 2: s = s2; d = d2; n = n2; break;
    case 3: s = s3; d = d3; n = n3; break;
    case 4: s = s4; d = d4; n = n4; break;
    default: s = s5; d = d5; n = n5; break;
  }
  const int i = (blockIdx.x * 256 + threadIdx.x) * 4;
  if (i < n) {
    float4 v = *(const float4*)(s + i);
    d[i + 0] = __float2bfloat16(v.x);
    d[i + 1] = __float2bfloat16(v.y);
    d[i + 2] = __float2bfloat16(v.z);
    d[i + 3] = __float2bfloat16(v.w);
  }
}

// ---------------------------------------------------------------------------
// EMA pass 1: local scan per 64-row chunk (carry-in 0). Exact decomposition:
// s_t = local_t + 0.9^(off+1) * carry_chunk, applied later in fuse_bf16.
// ---------------------------------------------------------------------------
__global__ __launch_bounds__(256)
void ema_scan(const float* __restrict__ x, float* __restrict__ l2)
{
  const int b  = blockIdx.z;
  const int t0 = blockIdx.y * 64;
  const int d  = blockIdx.x * 256 + threadIdx.x;
  const float* xp = x  + (size_t)b * T_ * D_ + d;
  float*       lp = l2 + (size_t)b * T_ * D_ + d;
  float s = 0.f;
  #pragma unroll 4
  for (int t = t0; t < t0 + 64; ++t) {
    s = 0.9f * s + 0.1f * xp[(size_t)t * D_];
    lp[(size_t)t * D_] = s;
  }
}

// ---------------------------------------------------------------------------
// EMA pass 2: carry[b,chunk,d] = s at end of previous chunk (global), via
// carry_c = localfinal_{c-1} + 0.9^64 * carry_{c-1};  carry_0 = 0.
// localfinal is just l2[chunk*64 - 1] from pass 1.
// ---------------------------------------------------------------------------
__global__ __launch_bounds__(256)
void ema_carry(const float* __restrict__ l2loc, float* __restrict__ carry)
{
  const int i = blockIdx.x * 256 + threadIdx.x;   // 0..4095
  const int b = i >> 11, d = i & 2047;
  const float A = 1.1790184577738583e-3f;          // 0.9^64
  float c = 0.f;
  carry[((size_t)b * 16 + 0) * D_ + d] = 0.f;
  for (int ch = 1; ch < 16; ++ch) {
    const float lf = l2loc[((size_t)b * T_ + ch * 64 - 1) * D_ + d];
    c = lf + A * c;
    carry[((size_t)b * 16 + ch) * D_ + d] = c;
  }
}

// ---------------------------------------------------------------------------
// Router head: lam = softmax(hdn @ rw2^T + rb2). One wave per row.
// ---------------------------------------------------------------------------
__global__ __launch_bounds__(256)
void router_kernel(const float* __restrict__ hdn, const float* __restrict__ rw2,
                   const float* __restrict__ rb2, float* __restrict__ lam)
{
  const int lane = threadIdx.x & 63;
  const int w    = threadIdx.x >> 6;
  const int m    = blockIdx.x * 4 + w;
  const float* hp = hdn + (size_t)m * DR_;
  float s0 = 0.f, s1 = 0.f, s2 = 0.f;
  for (int k = lane * 4; k < DR_; k += 256) {
    float4 h4 = *(const float4*)(hp + k);
    float4 w0 = *(const float4*)(rw2 + k);
    float4 w1 = *(const float4*)(rw2 + DR_ + k);
    float4 w2 = *(const float4*)(rw2 + 2 * DR_ + k);
    s0 += h4.x * w0.x + h4.y * w0.y + h4.z * w0.z + h4.w * w0.w;
    s1 += h4.x * w1.x + h4.y * w1.y + h4.z * w1.z + h4.w * w1.w;
    s2 += h4.x * w2.x + h4.y * w2.y + h4.z * w2.z + h4.w * w2.w;
  }
  #pragma unroll
  for (int off = 32; off > 0; off >>= 1) {
    s0 += __shfl_down(s0, off);
    s1 += __shfl_down(s1, off);
    s2 += __shfl_down(s2, off);
  }
  if (lane == 0) {
    s0 += rb2[0]; s1 += rb2[1]; s2 += rb2[2];
    float mx = fmaxf(s0, fmaxf(s1, s2));
    float e0 = __expf(s0 - mx), e1 = __expf(s1 - mx), e2 = __expf(s2 - mx);
    float inv = 1.f / (e0 + e1 + e2);
    lam[(size_t)m * 3 + 0] = e0 * inv;
    lam[(size_t)m * 3 + 1] = e1 * inv;
    lam[(size_t)m * 3 + 2] = e2 * inv;
  }
}

// ---------------------------------------------------------------------------
// fused = lam0*x + lam1*(l2local + 0.9^(off+1)*carry) + lam2*l3mem -> bf16
// ---------------------------------------------------------------------------
__global__ __launch_bounds__(256)
void fuse_bf16(const float* __restrict__ x, const float* __restrict__ l2,
               const float* __restrict__ l3m, const float* __restrict__ lam,
               const float* __restrict__ carry, __hip_bfloat16* __restrict__ fb)
{
  const int i4 = blockIdx.x * 256 + threadIdx.x;   // over M_*D_/4
  const int m  = i4 >> 9;                          // D_/4 = 512
  const int c  = (i4 & 511) << 2;
  const int b  = m >> 10;
  const int t  = m & 1023;
  const int ch = t >> 6, off = t & 63;
  const float p = __expf((float)(off + 1) * -0.105360515657f);  // 0.9^(off+1)
  const float w0 = lam[m * 3 + 0], w1 = lam[m * 3 + 1], w2 = lam[m * 3 + 2];
  const float4 xv = *(const float4*)(x   + (size_t)m * D_ + c);
  const float4 ev = *(const float4*)(l2  + (size_t)m * D_ + c);
  const float4 gv = *(const float4*)(l3m + (size_t)b * D_ + c);
  const float4 cv = *(const float4*)(carry + ((size_t)b * 16 + ch) * D_ + c);
  __hip_bfloat16* o = fb + (size_t)m * D_ + c;
  o[0] = __float2bfloat16(w0 * xv.x + w1 * (ev.x + p * cv.x) + w2 * gv.x);
  o[1] = __float2bfloat16(w0 * xv.y + w1 * (ev.y + p * cv.y) + w2 * gv.y);
  o[2] = __float2bfloat16(w0 * xv.z + w1 * (ev.z + p * cv.z) + w2 * gv.z);
  o[3] = __float2bfloat16(w0 * xv.w + w1 * (ev.w + p * cv.w) + w2 * gv.w);
}

// ---------------------------------------------------------------------------
// MFMA flash attention. 64-row Q-tile per block, 4 waves x 16 q-rows,
// 64-key K-tiles, 16x16x32 bf16 MFMA for QK^T and PV.
// qg: bf16 [M,D] row-major; kg: bf16 [b,h,t,dh]; vg: bf16 [b,h,dh,t] (pre-T);
// og: bf16 [b,t,d].
// ---------------------------------------------------------------------------
__global__ __launch_bounds__(256)
void flash_mfma(const __hip_bfloat16* __restrict__ qg,
                const __hip_bfloat16* __restrict__ kg,
                const __hip_bfloat16* __restrict__ vg,
                __hip_bfloat16* __restrict__ og)
{
  __shared__ __hip_bfloat16 Qs[64 * 136];
  __shared__ __hip_bfloat16 Ks[64 * 136];
  __shared__ __hip_bfloat16 Vt[128 * 72];
  __shared__ __hip_bfloat16 Ps[64 * 72];
  const int tid  = threadIdx.x;
  const int wave = tid >> 6, lane = tid & 63;
  const int qt = blockIdx.x, bh = blockIdx.y;
  const int b = bh >> 4, h = bh & 15;
  const int q0 = qt * 64;
  const int lo = lane & 15, hi = lane >> 4;

  {
    const __hip_bfloat16* qsrc = qg + (size_t)(b * T_ + q0) * D_ + h * DH_;
    #pragma unroll
    for (int i = 0; i < 4; ++i) {
      const int ci = tid + 256 * i;
      const int r = ci >> 4, j = ci & 15;
      short8 v = *(const short8*)(qsrc + (size_t)r * D_ + j * 8);
      *(short8*)&Qs[r * 136 + j * 8] = v;
    }
  }
  __syncthreads();
  short8 aq[4];
  #pragma unroll
  for (int kk = 0; kk < 4; ++kk)
    aq[kk] = *(const short8*)&Qs[(wave * 16 + lo) * 136 + kk * 32 + hi * 8];

  f32x4 oacc[8];
  #pragma unroll
  for (int i = 0; i < 8; ++i) oacc[i] = (f32x4)0.f;
  float mrow[4] = {-INFINITY, -INFINITY, -INFINITY, -INFINITY};
  float lrow[4] = {0.f, 0.f, 0.f, 0.f};

  const __hip_bfloat16* kbp = kg + (size_t)bh * T_ * DH_;
  const __hip_bfloat16* vbp = vg + (size_t)bh * DH_ * T_;
  const float scale = 0.08838834764831845f;      // 1/sqrt(128)

  for (int kt = 0; kt <= qt; ++kt) {
    const int k0 = kt * 64;
    __syncthreads();
    #pragma unroll
    for (int i = 0; i < 4; ++i) {
      const int ci = tid + 256 * i;
      const int r = ci >> 4, j = ci & 15;
      short8 v = *(const short8*)(kbp + (size_t)(k0 + r) * DH_ + j * 8);
      *(short8*)&Ks[r * 136 + j * 8] = v;
      const int dd = ci >> 3, j2 = ci & 7;
      short8 w = *(const short8*)(vbp + (size_t)dd * T_ + k0 + j2 * 8);
      *(short8*)&Vt[dd * 72 + j2 * 8] = w;
    }
    __syncthreads();

    f32x4 sc[4];
    #pragma unroll
    for (int nt = 0; nt < 4; ++nt) {
      sc[nt] = (f32x4)0.f;
      #pragma unroll
      for (int kk = 0; kk < 4; ++kk) {
        short8 bk = *(const short8*)&Ks[(nt * 16 + lo) * 136 + kk * 32 + hi * 8];
        sc[nt] = __builtin_amdgcn_mfma_f32_16x16x32_bf16(aq[kk], bk, sc[nt], 0, 0, 0);
      }
    }
    const int qrow = q0 + wave * 16 + hi * 4;
    #pragma unroll
    for (int nt = 0; nt < 4; ++nt) {
      const int key = k0 + nt * 16 + lo;
      #pragma unroll
      for (int r = 0; r < 4; ++r) {
        float v = sc[nt][r] * scale;
        sc[nt][r] = (key <= qrow + r) ? v : -1e30f;
      }
    }
    float alpha[4];
    #pragma unroll
    for (int r = 0; r < 4; ++r) {
      float mx = fmaxf(fmaxf(sc[0][r], sc[1][r]), fmaxf(sc[2][r], sc[3][r]));
      mx = fmaxf(mx, __shfl_xor(mx, 1));
      mx = fmaxf(mx, __shfl_xor(mx, 2));
      mx = fmaxf(mx, __shfl_xor(mx, 4));
      mx = fmaxf(mx, __shfl_xor(mx, 8));
      const float nm = fmaxf(mrow[r], mx);
      alpha[r] = __expf(mrow[r] - nm);
      mrow[r] = nm;
      float ls = 0.f;
      #pragma unroll
      for (int nt = 0; nt < 4; ++nt) {
        float p = __expf(sc[nt][r] - nm);
        sc[nt][r] = p;
        ls += p;
      }
      ls += __shfl_xor(ls, 1);
      ls += __shfl_xor(ls, 2);
      ls += __shfl_xor(ls, 4);
      ls += __shfl_xor(ls, 8);
      lrow[r] = lrow[r] * alpha[r] + ls;
    }
    #pragma unroll
    for (int nt = 0; nt < 4; ++nt)
      #pragma unroll
      for (int r = 0; r < 4; ++r)
        Ps[(wave * 16 + hi * 4 + r) * 72 + nt * 16 + lo] = __float2bfloat16(sc[nt][r]);
    #pragma unroll
    for (int n2 = 0; n2 < 8; ++n2)
      #pragma unroll
      for (int r = 0; r < 4; ++r) oacc[n2][r] *= alpha[r];
    short8 ap[2];
    #pragma unroll
    for (int k2 = 0; k2 < 2; ++k2)
      ap[k2] = *(const short8*)&Ps[(wave * 16 + lo) * 72 + k2 * 32 + hi * 8];
    #pragma unroll
    for (int n2 = 0; n2 < 8; ++n2) {
      #pragma unroll
      for (int k2 = 0; k2 < 2; ++k2) {
        short8 bv = *(const short8*)&Vt[(n2 * 16 + lo) * 72 + k2 * 32 + hi * 8];
        oacc[n2] = __builtin_amdgcn_mfma_f32_16x16x32_bf16(ap[k2], bv, oacc[n2], 0, 0, 0);
      }
    }
  }

  float inv[4];
  #pragma unroll
  for (int r = 0; r < 4; ++r) inv[r] = 1.f / lrow[r];
  __hip_bfloat16* od = og + (size_t)(b * T_ + q0 + wave * 16 + hi * 4) * D_ + h * DH_;
  #pragma unroll
  for (int n2 = 0; n2 < 8; ++n2)
    #pragma unroll
    for (int r = 0; r < 4; ++r)
      od[(size_t)r * D_ + n2 * 16 + lo] = __float2bfloat16(oacc[n2][r] * inv[r]);
}

// ---------------------------------------------------------------------------
extern "C" void kernel_launch(void* const* d_in, const int* in_sizes, int n_in,
                              void* d_out, int out_size, void* d_ws, size_t ws_size,
                              hipStream_t stream)
{
  const float* x   = (const float*)d_in[0];
  const float* l3m = (const float*)d_in[1];
  const float* wq  = (const float*)d_in[2];
  const float* wk  = (const float*)d_in[3];
  const float* wv  = (const float*)d_in[4];
  const float* wo  = (const float*)d_in[5];
  const float* rw1 = (const float*)d_in[6];
  const float* rb1 = (const float*)d_in[7];
  const float* rw2 = (const float*)d_in[8];
  const float* rb2 = (const float*)d_in[9];

  float* out = (float*)d_out;                 // [b,t,d]      4,194,304 f32
  float* kh  = out + 4194304;                 // [b,h,t,dh]   4,194,304 f32
  float* vh  = out + 8388608;                 // [b,h,t,dh]   4,194,304 f32
  float* lam = out + 12582912;                // [b,t,3]          6,144 f32

  // ws layout (80 MB):
  char* wsb = (char*)d_ws;
  float*          l2_f32 = (float*)(wsb);                        // 16 MB (local scan)
  float*          hdn    = (float*)(wsb + (16u << 20));          //  8 MB
  __hip_bfloat16* wkb    = (__hip_bfloat16*)(wsb + (24u << 20)); //  8 MB \ contiguous
  __hip_bfloat16* wvb    = (__hip_bfloat16*)(wsb + (32u << 20)); //  8 MB / [4096,2048]
  __hip_bfloat16* wob    = (__hip_bfloat16*)(wsb + (40u << 20)); //  8 MB
  __hip_bfloat16* fusedb = (__hip_bfloat16*)(wsb + (48u << 20)); //  8 MB
  __hip_bfloat16* attnb  = (__hip_bfloat16*)(wsb + (56u << 20)); //  8 MB (written step 9)
  __hip_bfloat16* khb    = (__hip_bfloat16*)(wsb + (64u << 20)); //  8 MB bf16 heads
  __hip_bfloat16* vtb    = (__hip_bfloat16*)(wsb + (72u << 20)); //  8 MB bf16 [b,h,dh,t]
  float*          carry  = (float*)attnb;   // 256 KB; dead before attnb written
  // d_out scratch reuse (regions written later in the stream order):
  __hip_bfloat16* wqb  = (__hip_bfloat16*)kh;                    // [16,24 MB) of d_out
  __hip_bfloat16* rw1b = (__hip_bfloat16*)kh + 4194304;          // [24,28 MB)
  __hip_bfloat16* xb   = (__hip_bfloat16*)vh;                    // [32,40 MB)
  __hip_bfloat16* qb   = (__hip_bfloat16*)out;                   // [0,8 MB); out written last

  dim3 blk(256);

  // 1. fp32->bf16: x, wq, wk, wv, wo, rw1
  cvt6<<<dim3(4096, 6), blk, 0, stream>>>(x, wq, wk, wv, wo, rw1,
                                          xb, wqb, wkb, wvb, wob, rw1b,
                                          M_ * D_, D_ * D_, D_ * D_, D_ * D_, D_ * D_, DR_ * D_);
  // 2. EMA pass1: local 64-chunk scans (exact; carry applied in fuse)
  ema_scan<<<dim3(8, 16, 2), blk, 0, stream>>>(x, l2_f32);
  // 3. EMA pass2: cross-chunk carries
  ema_carry<<<dim3(16), blk, 0, stream>>>(l2_f32, carry);
  // 4. qb = bf16(x @ wq^T)
  gemm_mfma<1, false><<<dim3(16, 16), blk, 0, stream>>>(xb, wqb, nullptr, nullptr, qb, nullptr, nullptr, M_, D_, D_);
  // 5. hdn = silu(q @ rw1^T + rb1)
  gemm_mfma<0, true><<<dim3(8, 16), blk, 0, stream>>>(qb, rw1b, rb1, hdn, nullptr, nullptr, nullptr, M_, DR_, D_);
  // 6. lam = softmax(hdn @ rw2^T + rb2)
  router_kernel<<<dim3(512), blk, 0, stream>>>(hdn, rw2, rb2, lam);
  // 7. fused = lam0*x + lam1*l2 + lam2*l3  -> bf16 (applies EMA carry)
  fuse_bf16<<<dim3(4096), blk, 0, stream>>>(x, l2_f32, l3m, lam, carry, fusedb);
  // 8. merged KV GEMM (N=4096): kh fp32+khb bf16 heads; vh fp32+vtb bf16 transposed
  gemm_mfma<4, false><<<dim3(32, 16), blk, 0, stream>>>(fusedb, wkb, nullptr, kh, khb, vh, vtb, M_, 2 * D_, D_);
  // 9. MFMA flash attention -> bf16 attnb [b,t,d]
  flash_mfma<<<dim3(16, 32), blk, 0, stream>>>(qb, khb, vtb, attnb);
  // 10. out = attn @ wo^T
  gemm_mfma<0, false><<<dim3(16, 16), blk, 0, stream>>>(attnb, wob, nullptr, out, nullptr, nullptr, nullptr, M_, D_, D_);
}